// Round 14
// baseline (81.780 us; speedup 1.0000x reference)
//
#include <hip/hip_runtime.h>
#include <hip/hip_bf16.h>

#define NN    8192
#define DD    512
#define SLOTS 128   // max supported degree; P(deg>128) ~ 0 for Poisson(~32)

typedef __attribute__((ext_vector_type(8))) short bf16x8;
typedef __attribute__((ext_vector_type(4))) float f32x4;

__device__ __forceinline__ unsigned short f2bf(float f) {
  union { float f; unsigned int u; } c; c.f = f;
  unsigned int u = c.u + 0x7fffu + ((c.u >> 16) & 1u);   // round-to-nearest-even
  return (unsigned short)(u >> 16);
}
__device__ __forceinline__ float bf2f(unsigned short h) {
  union { unsigned int u; float f; } c; c.u = ((unsigned int)h) << 16;
  return c.f;
}

// ---------------------------------------------------------------------------
// D1: fused GEMM (blocks [0,256)) ∥ A-scan (blocks [256,2304)).
// __launch_bounds__(256,4): 128-VGPR cap -> 4 blocks/CU (round-8 win).
// Scan unroll-8 (round-12 win) + NONTEMPORAL A loads (use-once stream; don't
// evict the GEMM's x/W/y working set from L2).
// ---------------------------------------------------------------------------
__global__ __launch_bounds__(256, 4) void k_fused(const float* __restrict__ A,
                                                  const float* __restrict__ x,
                                                  const float* __restrict__ W,
                                                  float* __restrict__ dinv,
                                                  int* __restrict__ nnz,
                                                  unsigned short* __restrict__ colidx,
                                                  unsigned short* __restrict__ y) {
  __shared__ unsigned short lA[128 * 72];           // 72 = 64 + 8 pad (GEMM branch)
  __shared__ unsigned short lB[128 * 72];
  const int bid  = blockIdx.x;
  const int t    = threadIdx.x;
  const int lane = t & 63;
  const int wid  = t >> 6;

  if (bid < 256) {
    // ---------------- GEMM branch: 128x128 tile, BK=64, 4 waves (2x2) -------
    const int wr = wid >> 1, wc = wid & 1;
    const int bm = (bid & 63) * 128;
    const int bn = (bid >> 6) * 128;
    f32x4 acc[4][4] = {};
    for (int ks = 0; ks < DD; ks += 64) {
      __syncthreads();                              // LDS safe to overwrite
      #pragma unroll
      for (int q = 0; q < 4; ++q) {
        const int c   = q * 256 + t;                // 8-elem chunk id, 0..1023
        const int row = c >> 3;
        const int cc  = c & 7;
        const float4* gx = reinterpret_cast<const float4*>(x + (size_t)(bm + row) * DD + ks + cc * 8);
        float4 v0 = gx[0], v1 = gx[1];
        bf16x8 oa;
        oa[0] = (short)f2bf(v0.x); oa[1] = (short)f2bf(v0.y);
        oa[2] = (short)f2bf(v0.z); oa[3] = (short)f2bf(v0.w);
        oa[4] = (short)f2bf(v1.x); oa[5] = (short)f2bf(v1.y);
        oa[6] = (short)f2bf(v1.z); oa[7] = (short)f2bf(v1.w);
        *reinterpret_cast<bf16x8*>(&lA[row * 72 + cc * 8]) = oa;
        const float4* gw = reinterpret_cast<const float4*>(W + (size_t)(bn + row) * DD + ks + cc * 8);
        float4 u0 = gw[0], u1 = gw[1];
        bf16x8 ob;
        ob[0] = (short)f2bf(u0.x); ob[1] = (short)f2bf(u0.y);
        ob[2] = (short)f2bf(u0.z); ob[3] = (short)f2bf(u0.w);
        ob[4] = (short)f2bf(u1.x); ob[5] = (short)f2bf(u1.y);
        ob[6] = (short)f2bf(u1.z); ob[7] = (short)f2bf(u1.w);
        *reinterpret_cast<bf16x8*>(&lB[row * 72 + cc * 8]) = ob;
      }
      __syncthreads();                              // staging visible
      #pragma unroll
      for (int kk = 0; kk < 2; ++kk) {
        bf16x8 af[4], bg[4];
        const int ko = kk * 32 + ((lane >> 4) << 3);
        #pragma unroll
        for (int m = 0; m < 4; ++m) {
          int r = wr * 64 + m * 16 + (lane & 15);
          af[m] = *reinterpret_cast<const bf16x8*>(&lA[r * 72 + ko]);
        }
        #pragma unroll
        for (int n = 0; n < 4; ++n) {
          int r = wc * 64 + n * 16 + (lane & 15);
          bg[n] = *reinterpret_cast<const bf16x8*>(&lB[r * 72 + ko]);
        }
        #pragma unroll
        for (int m = 0; m < 4; ++m)
          #pragma unroll
          for (int n = 0; n < 4; ++n)
            acc[m][n] = __builtin_amdgcn_mfma_f32_16x16x32_bf16(af[m], bg[n], acc[m][n], 0, 0, 0);
      }
    }
    // C/D layout (m89-verified): col = lane&15, row = (lane>>4)*4 + j
    const int r0 = bm + wr * 64 + ((lane >> 4) << 2);
    const int c0 = bn + wc * 64 + (lane & 15);
    #pragma unroll
    for (int m = 0; m < 4; ++m)
      #pragma unroll
      for (int n = 0; n < 4; ++n)
        #pragma unroll
        for (int j = 0; j < 4; ++j)
          y[(size_t)(r0 + m * 16 + j) * DD + (c0 + n * 16)] = f2bf(acc[m][n][j]);
  } else {
    // ---------------- A-scan branch: one wave per row, unroll-8, nt loads --
    const int row = (bid - 256) * 4 + wid;          // 2048 blocks * 4 waves
    const f32x4* Arow = reinterpret_cast<const f32x4*>(A + (size_t)row * NN);
    unsigned short* ci = colidx + (size_t)row * SLOTS;
    const unsigned long long lt = (1ull << lane) - 1ull;
    int base = 0;
    for (int it = 0; it < 32; it += 8) {            // unroll-8: 2 KB/wave in flight
      f32x4 vv[8];
      #pragma unroll
      for (int u = 0; u < 8; ++u)
        vv[u] = __builtin_nontemporal_load(Arow + (it + u) * 64 + lane);
      #pragma unroll
      for (int u = 0; u < 8; ++u) {
        const int colbase = (it + u) * 256 + lane * 4;
        #pragma unroll
        for (int c = 0; c < 4; ++c) {
          float a = vv[u][c];
          unsigned long long m = __ballot(a != 0.0f);
          if (a != 0.0f) {
            int p = base + __popcll(m & lt);
            if (p < SLOTS) ci[p] = (unsigned short)(colbase + c);
          }
          base += __popcll(m);
        }
      }
    }
    if (lane == 0) {
      nnz[row]  = (base < SLOTS) ? base : SLOTS;
      dinv[row] = rsqrtf((float)base + 1.0f);       // deg = count + 1 (self loop)
    }
  }
}

// ---------------------------------------------------------------------------
// D2: out[i,:] = relu( d_i * ( d_i*y[i,:] + sum_j d_j*y[j,:] ) + b )  (fp32 out)
// MERGED column passes (round-14): grid 2048, one wave per row; each wave
// processes cols [0,256) then [256,512) sequentially, REUSING the LDS
// neighbor list (halves colidx/dinv/LDS-fill cost and block tails vs the
// round-10 2-grid split; blocks stay in rough lockstep so the column-phase
// L2 locality is preserved). unroll-8 gathers; ascending sum order per
// column -> bit-identical. Nontemporal f32x4 output stores.
// ---------------------------------------------------------------------------
__global__ __launch_bounds__(256) void k_aggregate(const unsigned short* __restrict__ y,
                                                   const float* __restrict__ dinv,
                                                   const int* __restrict__ nnz,
                                                   const unsigned short* __restrict__ colidx,
                                                   const float* __restrict__ bias,
                                                   float* __restrict__ out) {
  const int t    = threadIdx.x;
  const int lane = t & 63;
  const int wid  = t >> 6;
  const int row  = blockIdx.x * 4 + wid;            // 2048 blocks * 4 waves
  __shared__ int   sj[4][SLOTS];
  __shared__ float sw[4][SLOTS];
  const int cnt = nnz[row];
  for (int p = lane; p < cnt; p += 64) {            // <=2 rounds (cnt <= 128)
    int j = colidx[(size_t)row * SLOTS + p];
    sj[wid][p] = j;
    sw[wid][p] = dinv[j];
  }
  __syncthreads();
  const float di = dinv[row];
  #pragma unroll 1                                  // keep halves sequential
  for (int half = 0; half < 2; ++half) {
    const size_t lofs = (size_t)(half * 256 + lane * 4);  // lane's 4 cols this half
    uint2 self = *reinterpret_cast<const uint2*>(y + (size_t)row * DD + lofs);
    float a[4];
    a[0] = di * bf2f((unsigned short)(self.x & 0xffffu));
    a[1] = di * bf2f((unsigned short)(self.x >> 16));
    a[2] = di * bf2f((unsigned short)(self.y & 0xffffu));
    a[3] = di * bf2f((unsigned short)(self.y >> 16));
    int i = 0;
    for (; i + 8 <= cnt; i += 8) {
      uint2 v0 = *reinterpret_cast<const uint2*>(y + (size_t)sj[wid][i + 0] * DD + lofs);
      uint2 v1 = *reinterpret_cast<const uint2*>(y + (size_t)sj[wid][i + 1] * DD + lofs);
      uint2 v2 = *reinterpret_cast<const uint2*>(y + (size_t)sj[wid][i + 2] * DD + lofs);
      uint2 v3 = *reinterpret_cast<const uint2*>(y + (size_t)sj[wid][i + 3] * DD + lofs);
      uint2 v4 = *reinterpret_cast<const uint2*>(y + (size_t)sj[wid][i + 4] * DD + lofs);
      uint2 v5 = *reinterpret_cast<const uint2*>(y + (size_t)sj[wid][i + 5] * DD + lofs);
      uint2 v6 = *reinterpret_cast<const uint2*>(y + (size_t)sj[wid][i + 6] * DD + lofs);
      uint2 v7 = *reinterpret_cast<const uint2*>(y + (size_t)sj[wid][i + 7] * DD + lofs);
      float w0 = sw[wid][i + 0], w1 = sw[wid][i + 1], w2 = sw[wid][i + 2], w3 = sw[wid][i + 3];
      float w4 = sw[wid][i + 4], w5 = sw[wid][i + 5], w6 = sw[wid][i + 6], w7 = sw[wid][i + 7];
      a[0] += w0 * bf2f((unsigned short)(v0.x & 0xffffu));
      a[1] += w0 * bf2f((unsigned short)(v0.x >> 16));
      a[2] += w0 * bf2f((unsigned short)(v0.y & 0xffffu));
      a[3] += w0 * bf2f((unsigned short)(v0.y >> 16));
      a[0] += w1 * bf2f((unsigned short)(v1.x & 0xffffu));
      a[1] += w1 * bf2f((unsigned short)(v1.x >> 16));
      a[2] += w1 * bf2f((unsigned short)(v1.y & 0xffffu));
      a[3] += w1 * bf2f((unsigned short)(v1.y >> 16));
      a[0] += w2 * bf2f((unsigned short)(v2.x & 0xffffu));
      a[1] += w2 * bf2f((unsigned short)(v2.x >> 16));
      a[2] += w2 * bf2f((unsigned short)(v2.y & 0xffffu));
      a[3] += w2 * bf2f((unsigned short)(v2.y >> 16));
      a[0] += w3 * bf2f((unsigned short)(v3.x & 0xffffu));
      a[1] += w3 * bf2f((unsigned short)(v3.x >> 16));
      a[2] += w3 * bf2f((unsigned short)(v3.y & 0xffffu));
      a[3] += w3 * bf2f((unsigned short)(v3.y >> 16));
      a[0] += w4 * bf2f((unsigned short)(v4.x & 0xffffu));
      a[1] += w4 * bf2f((unsigned short)(v4.x >> 16));
      a[2] += w4 * bf2f((unsigned short)(v4.y & 0xffffu));
      a[3] += w4 * bf2f((unsigned short)(v4.y >> 16));
      a[0] += w5 * bf2f((unsigned short)(v5.x & 0xffffu));
      a[1] += w5 * bf2f((unsigned short)(v5.x >> 16));
      a[2] += w5 * bf2f((unsigned short)(v5.y & 0xffffu));
      a[3] += w5 * bf2f((unsigned short)(v5.y >> 16));
      a[0] += w6 * bf2f((unsigned short)(v6.x & 0xffffu));
      a[1] += w6 * bf2f((unsigned short)(v6.x >> 16));
      a[2] += w6 * bf2f((unsigned short)(v6.y & 0xffffu));
      a[3] += w6 * bf2f((unsigned short)(v6.y >> 16));
      a[0] += w7 * bf2f((unsigned short)(v7.x & 0xffffu));
      a[1] += w7 * bf2f((unsigned short)(v7.x >> 16));
      a[2] += w7 * bf2f((unsigned short)(v7.y & 0xffffu));
      a[3] += w7 * bf2f((unsigned short)(v7.y >> 16));
    }
    for (; i < cnt; ++i) {
      int j = sj[wid][i]; float w = sw[wid][i];
      uint2 v = *reinterpret_cast<const uint2*>(y + (size_t)j * DD + lofs);
      a[0] += w * bf2f((unsigned short)(v.x & 0xffffu));
      a[1] += w * bf2f((unsigned short)(v.x >> 16));
      a[2] += w * bf2f((unsigned short)(v.y & 0xffffu));
      a[3] += w * bf2f((unsigned short)(v.y >> 16));
    }
    const float4 bb = reinterpret_cast<const float4*>(bias)[half * 64 + lane];
    f32x4 o;
    o[0] = fmaxf(di * a[0] + bb.x, 0.0f);
    o[1] = fmaxf(di * a[1] + bb.y, 0.0f);
    o[2] = fmaxf(di * a[2] + bb.z, 0.0f);
    o[3] = fmaxf(di * a[3] + bb.w, 0.0f);
    // nontemporal: don't let the output stream evict y from L2
    __builtin_nontemporal_store(o, reinterpret_cast<f32x4*>(out + (size_t)row * DD + lofs));
  }
}

// ---------------------------------------------------------------------------
extern "C" void kernel_launch(void* const* d_in, const int* in_sizes, int n_in,
                              void* d_out, int out_size, void* d_ws, size_t ws_size,
                              hipStream_t stream) {
  // identify inputs by element count (all distinct)
  const float* x = nullptr; const float* A = nullptr;
  const float* W = nullptr; const float* b = nullptr;
  for (int i = 0; i < n_in; ++i) {
    if      (in_sizes[i] == NN * DD) x = (const float*)d_in[i];
    else if (in_sizes[i] == NN * NN) A = (const float*)d_in[i];
    else if (in_sizes[i] == DD * DD) W = (const float*)d_in[i];
    else if (in_sizes[i] == DD)      b = (const float*)d_in[i];
  }

  char* ws = (char*)d_ws;
  // ws layout (bytes), total ~10.6 MB:
  //   y      bf16 [8192*512]   @ 0          (8,388,608)
  //   dinv   f32  [8192]       @ 8,388,608  (32,768)
  //   nnz    i32  [8192]       @ 8,421,376  (32,768)
  //   colidx u16  [8192*SLOTS] @ 8,454,144  (2,097,152)
  unsigned short* y      = (unsigned short*)(ws);
  float*          dinv   = (float*)(ws + 8388608);
  int*            nnz    = (int*)(ws + 8421376);
  unsigned short* colidx = (unsigned short*)(ws + 8454144);
  float*          out    = (float*)d_out;           // fp32 output (reference dtype)

  hipLaunchKernelGGL(k_fused,     dim3(2304), dim3(256), 0, stream, A, x, W, dinv, nnz, colidx, y);
  hipLaunchKernelGGL(k_aggregate, dim3(2048), dim3(256), 0, stream, y, dinv, nnz, colidx, b, out);
}

// Round 15
// 76.823 us; speedup vs baseline: 1.0645x; 1.0645x over previous
//
#include <hip/hip_runtime.h>
#include <hip/hip_bf16.h>

#define NN    8192
#define DD    512
#define SLOTS 128   // max supported degree; P(deg>128) ~ 0 for Poisson(~32)

typedef __attribute__((ext_vector_type(8))) short bf16x8;
typedef __attribute__((ext_vector_type(4))) float f32x4;

__device__ __forceinline__ unsigned short f2bf(float f) {
  union { float f; unsigned int u; } c; c.f = f;
  unsigned int u = c.u + 0x7fffu + ((c.u >> 16) & 1u);   // round-to-nearest-even
  return (unsigned short)(u >> 16);
}
__device__ __forceinline__ float bf2f(unsigned short h) {
  union { unsigned int u; float f; } c; c.u = ((unsigned int)h) << 16;
  return c.f;
}

// ---------------------------------------------------------------------------
// D1: fused GEMM (blocks [0,256)) ∥ A-scan (blocks [256,2304)).
// __launch_bounds__(256,4): 128-VGPR cap -> 4 blocks/CU (round-8 win).
// Scan unroll-8: 2 KB/wave in flight (round-12 win). Plain loads (round-14's
// nontemporal A loads were part of a 5 µs regression — reverted).
// ---------------------------------------------------------------------------
__global__ __launch_bounds__(256, 4) void k_fused(const float* __restrict__ A,
                                                  const float* __restrict__ x,
                                                  const float* __restrict__ W,
                                                  float* __restrict__ dinv,
                                                  int* __restrict__ nnz,
                                                  unsigned short* __restrict__ colidx,
                                                  unsigned short* __restrict__ y) {
  __shared__ unsigned short lA[128 * 72];           // 72 = 64 + 8 pad (GEMM branch)
  __shared__ unsigned short lB[128 * 72];
  const int bid  = blockIdx.x;
  const int t    = threadIdx.x;
  const int lane = t & 63;
  const int wid  = t >> 6;

  if (bid < 256) {
    // ---------------- GEMM branch: 128x128 tile, BK=64, 4 waves (2x2) -------
    const int wr = wid >> 1, wc = wid & 1;
    const int bm = (bid & 63) * 128;
    const int bn = (bid >> 6) * 128;
    f32x4 acc[4][4] = {};
    for (int ks = 0; ks < DD; ks += 64) {
      __syncthreads();                              // LDS safe to overwrite
      #pragma unroll
      for (int q = 0; q < 4; ++q) {
        const int c   = q * 256 + t;                // 8-elem chunk id, 0..1023
        const int row = c >> 3;
        const int cc  = c & 7;
        const float4* gx = reinterpret_cast<const float4*>(x + (size_t)(bm + row) * DD + ks + cc * 8);
        float4 v0 = gx[0], v1 = gx[1];
        bf16x8 oa;
        oa[0] = (short)f2bf(v0.x); oa[1] = (short)f2bf(v0.y);
        oa[2] = (short)f2bf(v0.z); oa[3] = (short)f2bf(v0.w);
        oa[4] = (short)f2bf(v1.x); oa[5] = (short)f2bf(v1.y);
        oa[6] = (short)f2bf(v1.z); oa[7] = (short)f2bf(v1.w);
        *reinterpret_cast<bf16x8*>(&lA[row * 72 + cc * 8]) = oa;
        const float4* gw = reinterpret_cast<const float4*>(W + (size_t)(bn + row) * DD + ks + cc * 8);
        float4 u0 = gw[0], u1 = gw[1];
        bf16x8 ob;
        ob[0] = (short)f2bf(u0.x); ob[1] = (short)f2bf(u0.y);
        ob[2] = (short)f2bf(u0.z); ob[3] = (short)f2bf(u0.w);
        ob[4] = (short)f2bf(u1.x); ob[5] = (short)f2bf(u1.y);
        ob[6] = (short)f2bf(u1.z); ob[7] = (short)f2bf(u1.w);
        *reinterpret_cast<bf16x8*>(&lB[row * 72 + cc * 8]) = ob;
      }
      __syncthreads();                              // staging visible
      #pragma unroll
      for (int kk = 0; kk < 2; ++kk) {
        bf16x8 af[4], bg[4];
        const int ko = kk * 32 + ((lane >> 4) << 3);
        #pragma unroll
        for (int m = 0; m < 4; ++m) {
          int r = wr * 64 + m * 16 + (lane & 15);
          af[m] = *reinterpret_cast<const bf16x8*>(&lA[r * 72 + ko]);
        }
        #pragma unroll
        for (int n = 0; n < 4; ++n) {
          int r = wc * 64 + n * 16 + (lane & 15);
          bg[n] = *reinterpret_cast<const bf16x8*>(&lB[r * 72 + ko]);
        }
        #pragma unroll
        for (int m = 0; m < 4; ++m)
          #pragma unroll
          for (int n = 0; n < 4; ++n)
            acc[m][n] = __builtin_amdgcn_mfma_f32_16x16x32_bf16(af[m], bg[n], acc[m][n], 0, 0, 0);
      }
    }
    // C/D layout (m89-verified): col = lane&15, row = (lane>>4)*4 + j
    const int r0 = bm + wr * 64 + ((lane >> 4) << 2);
    const int c0 = bn + wc * 64 + (lane & 15);
    #pragma unroll
    for (int m = 0; m < 4; ++m)
      #pragma unroll
      for (int n = 0; n < 4; ++n)
        #pragma unroll
        for (int j = 0; j < 4; ++j)
          y[(size_t)(r0 + m * 16 + j) * DD + (c0 + n * 16)] = f2bf(acc[m][n][j]);
  } else {
    // ---------------- A-scan branch: one wave per row, unroll-8 ------------
    const int row = (bid - 256) * 4 + wid;          // 2048 blocks * 4 waves
    const float4* Arow = reinterpret_cast<const float4*>(A + (size_t)row * NN);
    unsigned short* ci = colidx + (size_t)row * SLOTS;
    const unsigned long long lt = (1ull << lane) - 1ull;
    int base = 0;
    for (int it = 0; it < 32; it += 8) {            // unroll-8: 2 KB/wave in flight
      float4 va = Arow[(it + 0) * 64 + lane];
      float4 vb = Arow[(it + 1) * 64 + lane];
      float4 vc = Arow[(it + 2) * 64 + lane];
      float4 vd = Arow[(it + 3) * 64 + lane];
      float4 ve = Arow[(it + 4) * 64 + lane];
      float4 vf = Arow[(it + 5) * 64 + lane];
      float4 vg = Arow[(it + 6) * 64 + lane];
      float4 vh = Arow[(it + 7) * 64 + lane];
      #pragma unroll
      for (int u = 0; u < 8; ++u) {
        float4 v = (u == 0) ? va : (u == 1) ? vb : (u == 2) ? vc : (u == 3) ? vd
                 : (u == 4) ? ve : (u == 5) ? vf : (u == 6) ? vg : vh;
        const int colbase = (it + u) * 256 + lane * 4;
        #pragma unroll
        for (int c = 0; c < 4; ++c) {
          float a = (c == 0) ? v.x : (c == 1) ? v.y : (c == 2) ? v.z : v.w;
          unsigned long long m = __ballot(a != 0.0f);
          if (a != 0.0f) {
            int p = base + __popcll(m & lt);
            if (p < SLOTS) ci[p] = (unsigned short)(colbase + c);
          }
          base += __popcll(m);
        }
      }
    }
    if (lane == 0) {
      nnz[row]  = (base < SLOTS) ? base : SLOTS;
      dinv[row] = rsqrtf((float)base + 1.0f);       // deg = count + 1 (self loop)
    }
  }
}

// ---------------------------------------------------------------------------
// D2 (round-10/12 winner, exact): 2-pass column split via grid (blocks
// [0,2048) = cols [0,256), [2048,4096) = cols [256,512)); dispatcher's
// in-order block issue gives temporal phase separation. Lane owns 4 cols
// (uint2 = 8 B); unroll-4 gather; nontemporal f32x4 output stores.
// Fixed ascending sum order -> bit-identical output.
// ---------------------------------------------------------------------------
__global__ __launch_bounds__(256) void k_aggregate(const unsigned short* __restrict__ y,
                                                   const float* __restrict__ dinv,
                                                   const int* __restrict__ nnz,
                                                   const unsigned short* __restrict__ colidx,
                                                   const float* __restrict__ bias,
                                                   float* __restrict__ out) {
  const int t    = threadIdx.x;
  const int lane = t & 63;
  const int wid  = t >> 6;
  const int pass = blockIdx.x >> 11;                // 0: cols 0-255, 1: cols 256-511
  const int row  = (blockIdx.x & 2047) * 4 + wid;   // one wave per row
  const int colb = pass * 256;
  __shared__ int   sj[4][SLOTS];
  __shared__ float sw[4][SLOTS];
  const int cnt = nnz[row];
  for (int p = lane; p < cnt; p += 64) {            // <=2 rounds (cnt <= 128)
    int j = colidx[(size_t)row * SLOTS + p];
    sj[wid][p] = j;
    sw[wid][p] = dinv[j];
  }
  __syncthreads();
  const float di = dinv[row];
  // lane owns cols [colb + lane*4, +4): uint2 = 4 bf16 = 8 B
  const size_t lofs = (size_t)(colb + lane * 4);    // element offset within a row
  uint2 self = *reinterpret_cast<const uint2*>(y + (size_t)row * DD + lofs);
  float a[4];
  a[0] = di * bf2f((unsigned short)(self.x & 0xffffu));
  a[1] = di * bf2f((unsigned short)(self.x >> 16));
  a[2] = di * bf2f((unsigned short)(self.y & 0xffffu));
  a[3] = di * bf2f((unsigned short)(self.y >> 16));
  int i = 0;
  for (; i + 4 <= cnt; i += 4) {
    int j0 = sj[wid][i], j1 = sj[wid][i + 1], j2 = sj[wid][i + 2], j3 = sj[wid][i + 3];
    float w0 = sw[wid][i], w1 = sw[wid][i + 1], w2 = sw[wid][i + 2], w3 = sw[wid][i + 3];
    uint2 v0 = *reinterpret_cast<const uint2*>(y + (size_t)j0 * DD + lofs);
    uint2 v1 = *reinterpret_cast<const uint2*>(y + (size_t)j1 * DD + lofs);
    uint2 v2 = *reinterpret_cast<const uint2*>(y + (size_t)j2 * DD + lofs);
    uint2 v3 = *reinterpret_cast<const uint2*>(y + (size_t)j3 * DD + lofs);
    a[0] += w0 * bf2f((unsigned short)(v0.x & 0xffffu));
    a[1] += w0 * bf2f((unsigned short)(v0.x >> 16));
    a[2] += w0 * bf2f((unsigned short)(v0.y & 0xffffu));
    a[3] += w0 * bf2f((unsigned short)(v0.y >> 16));
    a[0] += w1 * bf2f((unsigned short)(v1.x & 0xffffu));
    a[1] += w1 * bf2f((unsigned short)(v1.x >> 16));
    a[2] += w1 * bf2f((unsigned short)(v1.y & 0xffffu));
    a[3] += w1 * bf2f((unsigned short)(v1.y >> 16));
    a[0] += w2 * bf2f((unsigned short)(v2.x & 0xffffu));
    a[1] += w2 * bf2f((unsigned short)(v2.x >> 16));
    a[2] += w2 * bf2f((unsigned short)(v2.y & 0xffffu));
    a[3] += w2 * bf2f((unsigned short)(v2.y >> 16));
    a[0] += w3 * bf2f((unsigned short)(v3.x & 0xffffu));
    a[1] += w3 * bf2f((unsigned short)(v3.x >> 16));
    a[2] += w3 * bf2f((unsigned short)(v3.y & 0xffffu));
    a[3] += w3 * bf2f((unsigned short)(v3.y >> 16));
  }
  for (; i < cnt; ++i) {
    int j = sj[wid][i]; float w = sw[wid][i];
    uint2 v = *reinterpret_cast<const uint2*>(y + (size_t)j * DD + lofs);
    a[0] += w * bf2f((unsigned short)(v.x & 0xffffu));
    a[1] += w * bf2f((unsigned short)(v.x >> 16));
    a[2] += w * bf2f((unsigned short)(v.y & 0xffffu));
    a[3] += w * bf2f((unsigned short)(v.y >> 16));
  }
  const float4 bb = reinterpret_cast<const float4*>(bias)[(colb >> 2) + lane];
  f32x4 o;
  o[0] = fmaxf(di * a[0] + bb.x, 0.0f);
  o[1] = fmaxf(di * a[1] + bb.y, 0.0f);
  o[2] = fmaxf(di * a[2] + bb.z, 0.0f);
  o[3] = fmaxf(di * a[3] + bb.w, 0.0f);
  // nontemporal: don't let the 8.4 MB/pass output stream evict y from L2
  __builtin_nontemporal_store(o, reinterpret_cast<f32x4*>(out + (size_t)row * DD + lofs));
}

// ---------------------------------------------------------------------------
extern "C" void kernel_launch(void* const* d_in, const int* in_sizes, int n_in,
                              void* d_out, int out_size, void* d_ws, size_t ws_size,
                              hipStream_t stream) {
  // identify inputs by element count (all distinct)
  const float* x = nullptr; const float* A = nullptr;
  const float* W = nullptr; const float* b = nullptr;
  for (int i = 0; i < n_in; ++i) {
    if      (in_sizes[i] == NN * DD) x = (const float*)d_in[i];
    else if (in_sizes[i] == NN * NN) A = (const float*)d_in[i];
    else if (in_sizes[i] == DD * DD) W = (const float*)d_in[i];
    else if (in_sizes[i] == DD)      b = (const float*)d_in[i];
  }

  char* ws = (char*)d_ws;
  // ws layout (bytes), total ~10.6 MB:
  //   y      bf16 [8192*512]   @ 0          (8,388,608)
  //   dinv   f32  [8192]       @ 8,388,608  (32,768)
  //   nnz    i32  [8192]       @ 8,421,376  (32,768)
  //   colidx u16  [8192*SLOTS] @ 8,454,144  (2,097,152)
  unsigned short* y      = (unsigned short*)(ws);
  float*          dinv   = (float*)(ws + 8388608);
  int*            nnz    = (int*)(ws + 8421376);
  unsigned short* colidx = (unsigned short*)(ws + 8454144);
  float*          out    = (float*)d_out;           // fp32 output (reference dtype)

  hipLaunchKernelGGL(k_fused,     dim3(2304), dim3(256), 0, stream, A, x, W, dinv, nnz, colidx, y);
  hipLaunchKernelGGL(k_aggregate, dim3(4096), dim3(256), 0, stream, y, dinv, nnz, colidx, b, out);
}